// Round 5
// baseline (1074.222 us; speedup 1.0000x reference)
//
#include <hip/hip_runtime.h>
#include <hip/hip_bf16.h>
#include <math.h>

#define BNROWS (4096*32)   // 131072
#define RB     64          // rows per block (= 2 SVGD states)
#define LN32   3.4657359027997265f

typedef __attribute__((ext_vector_type(8))) short bf16x8;
typedef __attribute__((ext_vector_type(4))) float f32x4;

static __device__ __forceinline__ ushort f2bf(float x) {
    union { __hip_bfloat16 h; ushort u; } cv;
    cv.h = __float2bfloat16(x);
    return cv.u;
}

// ---------------------------------------------------------------------------
// Pack weights into MFMA B-fragment order (lane-contiguous 16B loads).
//   group g = (tile*C + c)*64 + lane ; elements g*8+j ; lane=(q<<4)|m
//   B[k = c*32 + q*8 + j][n = tile*16 + m]
__global__ void prep_pack(const float* __restrict__ w1,
                          const float* __restrict__ w2,
                          ushort* __restrict__ pB1, ushort* __restrict__ pB2,
                          ushort* __restrict__ pB3, ushort* __restrict__ pB4) {
    int g = blockIdx.x * 256 + threadIdx.x;   // 19968 total
    ushort out[8];
    ushort* dst;
    if (g < 3072) {
        int lane = g & 63, gc = g >> 6;
        int t = gc / 3, c = gc % 3;
        int m = lane & 15, q = lane >> 4, n = t * 16 + m;
        #pragma unroll
        for (int j = 0; j < 8; ++j) {
            int k = c * 32 + q * 8 + j;
            out[j] = f2bf((k < 80) ? w1[k * 256 + n] : 0.f);
        }
        dst = &pB1[g * 8];
    } else if (g < 11264) {
        int gg = g - 3072;
        int lane = gg & 63, gc = gg >> 6;
        int t = gc >> 3, c = gc & 7;
        int m = lane & 15, q = lane >> 4, n = t * 16 + m;
        #pragma unroll
        for (int j = 0; j < 8; ++j)
            out[j] = f2bf(w2[(c * 32 + q * 8 + j) * 256 + n]);
        dst = &pB2[gg * 8];
    } else if (g < 19456) {
        int gg = g - 11264;
        int lane = gg & 63, gc = gg >> 6;
        int t = gc >> 3, c = gc & 7;
        int m = lane & 15, q = lane >> 4;
        #pragma unroll
        for (int j = 0; j < 8; ++j)
            out[j] = f2bf(w2[(t * 16 + m) * 256 + c * 32 + q * 8 + j]);
        dst = &pB3[gg * 8];
    } else if (g < 19968) {
        int gg = g - 19456;
        int lane = gg & 63, c = gg >> 6;
        int m = lane & 15, q = lane >> 4;
        #pragma unroll
        for (int j = 0; j < 8; ++j)
            out[j] = f2bf(w1[(64 + m) * 256 + c * 32 + q * 8 + j]);
        dst = &pB4[gg * 8];
    } else return;
    *(uint4*)dst = *(uint4*)out;
}

// ---------------------------------------------------------------------------
// Fully fused 3-step SVGD sampler. One block = 64 rows = 2 states.
// Per step: bf16-MFMA critic fwd+bwd (phases B..E) entirely in LDS, then
// inline SVGD (2 states in parallel, 128 threads each, bit-exact radix-select
// median). No intermediate HBM traffic.
// launch_bounds(256,2): 256-reg budget — round-4's (256,3) caused ~150 MB of
// scratch spill traffic per dispatch. Do not tighten.
__global__ __launch_bounds__(256, 2) void fused_kernel(
    const float* __restrict__ obs,   // [BN,64]
    const float* __restrict__ a0,    // [BN,16]
    const float* __restrict__ b1,    // [256]
    const float* __restrict__ b2,    // [256]
    const float* __restrict__ w3,    // [256]
    const float* __restrict__ b3,    // [1]
    const ushort* __restrict__ pB1, const ushort* __restrict__ pB2,
    const ushort* __restrict__ pB3, const ushort* __restrict__ pB4,
    float* __restrict__ out_a,       // [BN,16]
    float* __restrict__ out_logp,    // [BN]
    float* __restrict__ out_q)       // [BN]
{
    __shared__ __align__(16) ushort B1s[RB * 104];   // h0 bf16 (persists; a-cols updated per step)
    __shared__ __align__(16) char   B0raw[RB * 264 * 2]; // h1/dz2/dz1 (mlp) | D2/KM/P/hist (svgd)
    __shared__ float XA[RB * 17];    // current actions fp32
    __shared__ float SS[RB * 17];    // scores fp32
    __shared__ float LG[RB];         // logp accumulator
    __shared__ float qpart[4][RB];
    __shared__ float medsh[2];
    __shared__ int   bbin[2], bexcl[2], wsumS[2][2], redc[2][2];
    __shared__ unsigned redm[2][2];

    ushort* B0u = (ushort*)B0raw;
    float*  D2a = (float*)B0raw;          // [2][32*33]
    float*  KMa = D2a + 2112;
    float*  PPa = KMa + 2112;
    int*    hista = (int*)(PPa + 2112);   // [2][256]  (ends at 27392 B < 33792)

    const int tid  = threadIdx.x;
    const int row0 = blockIdx.x * RB;

    // ---- one-time staging: obs -> B1 bf16, a0 -> XA + B1, pad, LG=0
    for (int u = tid; u < RB * 16; u += 256) {
        int r = u >> 4, c4 = (u & 15) * 4;
        float4 vv = *(const float4*)&obs[(size_t)(row0 + r) * 64 + c4];
        ushort4 o; o.x = f2bf(vv.x); o.y = f2bf(vv.y); o.z = f2bf(vv.z); o.w = f2bf(vv.w);
        *(ushort4*)&B1s[r * 104 + c4] = o;
    }
    {
        int r = tid >> 2, d0 = (tid & 3) * 4;
        float4 av = *(const float4*)&a0[(size_t)(row0 + r) * 16 + d0];
        XA[r * 17 + d0 + 0] = av.x; XA[r * 17 + d0 + 1] = av.y;
        XA[r * 17 + d0 + 2] = av.z; XA[r * 17 + d0 + 3] = av.w;
        ushort4 pv; pv.x = f2bf(av.x); pv.y = f2bf(av.y); pv.z = f2bf(av.z); pv.w = f2bf(av.w);
        *(ushort4*)&B1s[r * 104 + 64 + d0] = pv;
        ushort4 zv; zv.x = zv.y = zv.z = zv.w = 0;
        *(ushort4*)&B1s[r * 104 + 80 + d0] = zv;
    }
    if (tid < RB) LG[tid] = 0.f;
    __syncthreads();

    const int lane = tid & 63;
    const int w    = tid >> 6;
    const int m    = lane & 15;
    const int q    = lane >> 4;
    const int qk   = q * 8;

    float b1v[4], b2v[4], w3v[4];
    #pragma unroll
    for (int tc = 0; tc < 4; ++tc) {
        b1v[tc] = b1[(w * 4 + tc) * 16 + m];
        b2v[tc] = b2[(w * 4 + tc) * 16 + m];
        w3v[tc] = w3[(w * 4 + tc) * 16 + m];
    }
    const float b3v = b3[0];

    // svgd thread mapping
    const int st = tid >> 7;          // state 0/1
    const int t  = tid & 127;         // thread within state
    const int lw = (tid >> 6) & 1;    // wave within state
    float* D2s = D2a + st * 1056;
    float* KMs = KMa + st * 1056;
    float* PPs = PPa + st * 1056;
    int*   hs  = hista + st * 256;
    const int rbase = st * 32;

    for (int step = 0; step < 3; ++step) {
        f32x4 acc[4][4];
        unsigned long long relumask = 0ULL;

        // ---- Phase B: z1 = h0 @ w1 + b1 ; relu -> B0u ; sign mask -> regs
        #pragma unroll
        for (int tc = 0; tc < 4; ++tc)
            #pragma unroll
            for (int rt = 0; rt < 4; ++rt)
                acc[rt][tc] = (f32x4){b1v[tc], b1v[tc], b1v[tc], b1v[tc]};
        for (int c = 0; c < 3; ++c) {
            bf16x8 af[4];
            #pragma unroll
            for (int rt = 0; rt < 4; ++rt)
                af[rt] = *(const bf16x8*)&B1s[(rt * 16 + m) * 104 + c * 32 + qk];
            #pragma unroll
            for (int tc = 0; tc < 4; ++tc) {
                bf16x8 bfr = *(const bf16x8*)&pB1[(((w * 4 + tc) * 3 + c) * 64 + lane) * 8];
                #pragma unroll
                for (int rt = 0; rt < 4; ++rt)
                    acc[rt][tc] = __builtin_amdgcn_mfma_f32_16x16x32_bf16(af[rt], bfr, acc[rt][tc], 0, 0, 0);
            }
        }
        #pragma unroll
        for (int rt = 0; rt < 4; ++rt)
            #pragma unroll
            for (int tc = 0; tc < 4; ++tc)
                #pragma unroll
                for (int i = 0; i < 4; ++i) {
                    float z = acc[rt][tc][i];
                    if (z > 0.f) relumask |= 1ULL << (rt * 16 + tc * 4 + i);
                    B0u[(rt * 16 + q * 4 + i) * 264 + (w * 4 + tc) * 16 + m] =
                        f2bf(fmaxf(z, 0.f));
                }
        __syncthreads();

        // ---- Phase C: z2 = h1 @ w2 + b2 ; q partials ; dz2 -> B0u
        #pragma unroll
        for (int tc = 0; tc < 4; ++tc)
            #pragma unroll
            for (int rt = 0; rt < 4; ++rt)
                acc[rt][tc] = (f32x4){b2v[tc], b2v[tc], b2v[tc], b2v[tc]};
        for (int c = 0; c < 8; ++c) {
            bf16x8 af[4];
            #pragma unroll
            for (int rt = 0; rt < 4; ++rt)
                af[rt] = *(const bf16x8*)&B0u[(rt * 16 + m) * 264 + c * 32 + qk];
            #pragma unroll
            for (int tc = 0; tc < 4; ++tc) {
                bf16x8 bfr = *(const bf16x8*)&pB2[(((w * 4 + tc) * 8 + c) * 64 + lane) * 8];
                #pragma unroll
                for (int rt = 0; rt < 4; ++rt)
                    acc[rt][tc] = __builtin_amdgcn_mfma_f32_16x16x32_bf16(af[rt], bfr, acc[rt][tc], 0, 0, 0);
            }
        }
        __syncthreads();                       // h1 reads done
        {
            float qp[4][4] = {};
            #pragma unroll
            for (int tc = 0; tc < 4; ++tc) {
                #pragma unroll
                for (int rt = 0; rt < 4; ++rt)
                    #pragma unroll
                    for (int i = 0; i < 4; ++i) {
                        float z = acc[rt][tc][i];
                        float dz;
                        if (z > 0.f) { qp[rt][i] += z * w3v[tc]; dz = w3v[tc]; }
                        else         { dz = 0.f; }
                        B0u[(rt * 16 + q * 4 + i) * 264 + (w * 4 + tc) * 16 + m] = f2bf(dz);
                    }
            }
            #pragma unroll
            for (int rt = 0; rt < 4; ++rt)
                #pragma unroll
                for (int i = 0; i < 4; ++i) {
                    float vv = qp[rt][i];
                    vv += __shfl_xor(vv, 1); vv += __shfl_xor(vv, 2);
                    vv += __shfl_xor(vv, 4); vv += __shfl_xor(vv, 8);
                    if (m == 0) qpart[w][rt * 16 + q * 4 + i] = vv;
                }
        }
        __syncthreads();                       // dz2 visible

        if (step == 2 && tid < RB)
            out_q[row0 + tid] = qpart[0][tid] + qpart[1][tid] + qpart[2][tid] +
                                qpart[3][tid] + b3v;

        // ---- Phase D: dh1 = dz2 @ w2^T ; dz1 = dh1 * mask -> B0u
        #pragma unroll
        for (int tc = 0; tc < 4; ++tc)
            #pragma unroll
            for (int rt = 0; rt < 4; ++rt) acc[rt][tc] = (f32x4){0.f, 0.f, 0.f, 0.f};
        for (int c = 0; c < 8; ++c) {
            bf16x8 af[4];
            #pragma unroll
            for (int rt = 0; rt < 4; ++rt)
                af[rt] = *(const bf16x8*)&B0u[(rt * 16 + m) * 264 + c * 32 + qk];
            #pragma unroll
            for (int tc = 0; tc < 4; ++tc) {
                bf16x8 bfr = *(const bf16x8*)&pB3[(((w * 4 + tc) * 8 + c) * 64 + lane) * 8];
                #pragma unroll
                for (int rt = 0; rt < 4; ++rt)
                    acc[rt][tc] = __builtin_amdgcn_mfma_f32_16x16x32_bf16(af[rt], bfr, acc[rt][tc], 0, 0, 0);
            }
        }
        __syncthreads();                       // dz2 reads done
        #pragma unroll
        for (int rt = 0; rt < 4; ++rt)
            #pragma unroll
            for (int tc = 0; tc < 4; ++tc)
                #pragma unroll
                for (int i = 0; i < 4; ++i) {
                    float dz = (relumask >> (rt * 16 + tc * 4 + i)) & 1ULL
                               ? acc[rt][tc][i] : 0.f;
                    B0u[(rt * 16 + q * 4 + i) * 264 + (w * 4 + tc) * 16 + m] = f2bf(dz);
                }
        __syncthreads();

        // ---- Phase E: score = dz1 @ w1[64:80]^T -> SS (wave w -> row-tile w)
        {
            f32x4 acc2 = (f32x4){0.f, 0.f, 0.f, 0.f};
            for (int c = 0; c < 8; ++c) {
                bf16x8 af = *(const bf16x8*)&B0u[(w * 16 + m) * 264 + c * 32 + qk];
                bf16x8 bfr = *(const bf16x8*)&pB4[(c * 64 + lane) * 8];
                acc2 = __builtin_amdgcn_mfma_f32_16x16x32_bf16(af, bfr, acc2, 0, 0, 0);
            }
            #pragma unroll
            for (int i = 0; i < 4; ++i)
                SS[(w * 16 + q * 4 + i) * 17 + m] = acc2[i];
        }
        __syncthreads();                       // SS visible; B0u free for svgd

        // ================= inline SVGD (2 states in parallel) =============
        unsigned v[8];                         // this thread's 8 dist^2 (bits)
        #pragma unroll
        for (int u = 0; u < 8; ++u) {
            int idx = t + 128 * u, i = idx >> 5, j = idx & 31;
            float s = 0.f;
            #pragma unroll
            for (int d = 0; d < 16; ++d) {
                float df = XA[(rbase + i) * 17 + d] - XA[(rbase + j) * 17 + d];
                s += df * df;
            }
            D2s[i * 33 + j] = s;
            v[u] = __float_as_uint(s);
        }

        // radix select rank-511 (bit-exact jnp.median)
        unsigned prefix = 0;
        int rank = 511;
        for (int shift = 24; shift >= 0; shift -= 8) {
            hs[t] = 0; hs[t + 128] = 0;
            __syncthreads();
            unsigned him = (shift == 24) ? 0u : (0xFFFFFFFFu << (shift + 8));
            #pragma unroll
            for (int u = 0; u < 8; ++u)
                if ((v[u] & him) == prefix)
                    atomicAdd(&hs[(v[u] >> shift) & 255], 1);
            __syncthreads();
            int c0 = hs[2 * t], c1 = hs[2 * t + 1], ps = c0 + c1, inc = ps;
            #pragma unroll
            for (int off = 1; off < 64; off <<= 1) {
                int x = __shfl_up(inc, off, 64);
                if (lane >= off) inc += x;
            }
            if (lane == 63) wsumS[st][lw] = inc;
            __syncthreads();
            int incl = inc + ((lw == 1) ? wsumS[st][0] : 0);
            int ex0 = incl - ps, ex1 = incl - c1;
            if (c0 > 0 && rank >= ex0 && rank < ex0 + c0) { bbin[st] = 2 * t;     bexcl[st] = ex0; }
            if (c1 > 0 && rank >= ex1 && rank < ex1 + c1) { bbin[st] = 2 * t + 1; bexcl[st] = ex1; }
            __syncthreads();
            prefix |= ((unsigned)bbin[st]) << shift;
            rank -= bexcl[st];
        }
        const float v1 = __uint_as_float(prefix);

        // rank-512: v1 if count(<=v1)>=513 else min(x>v1)
        {
            int cle = 0; unsigned mgt = 0xFFFFFFFFu;
            #pragma unroll
            for (int u = 0; u < 8; ++u) {
                if (v[u] <= prefix) cle++;
                else mgt = min(mgt, v[u]);
            }
            #pragma unroll
            for (int off = 1; off < 64; off <<= 1) {
                cle += __shfl_xor(cle, off);
                mgt = min(mgt, (unsigned)__shfl_xor((int)mgt, off));
            }
            if (lane == 0) { redc[st][lw] = cle; redm[st][lw] = mgt; }
            __syncthreads();
            if (t == 0) {
                int C = redc[st][0] + redc[st][1];
                unsigned M = min(redm[st][0], redm[st][1]);
                float v2 = (C >= 513) ? v1 : __uint_as_float(M);
                medsh[st] = 0.5f * (v1 + v2);
            }
            __syncthreads();
        }
        const float gamma = 1.0f / (2.0f * (medsh[st] / LN32 + 1e-8f));

        // K and P
        #pragma unroll
        for (int u = 0; u < 8; ++u) {
            int idx = t + 128 * u, i = idx >> 5, j = idx & 31;
            KMs[i * 33 + j] = __expf(-gamma * __uint_as_float(v[u]));
            float p = 0.f;
            #pragma unroll
            for (int d = 0; d < 16; ++d)
                p += (XA[(rbase + i) * 17 + d] - XA[(rbase + j) * 17 + d]) *
                     SS[(rbase + j) * 17 + d];
            PPs[i * 33 + j] = p;
        }
        __syncthreads();

        // phi (4 outputs/thread) -> regs
        float av[4]; int ii[4], dd[4];
        #pragma unroll
        for (int u = 0; u < 4; ++u) {
            int idx = t + 128 * u, i = idx >> 4, d = idx & 15;
            ii[u] = i; dd[u] = d;
            float xi = XA[(rbase + i) * 17 + d];
            float s1 = 0.f, s2 = 0.f;
            #pragma unroll
            for (int j = 0; j < 32; ++j) {
                float kk = KMs[i * 33 + j];
                s1 += kk * SS[(rbase + j) * 17 + d];
                s2 += (xi - XA[(rbase + j) * 17 + d]) * kk;
            }
            float phi = (s1 + 2.f * gamma * s2) * (1.f / 32.f);
            float a2 = xi + 0.1f * phi;
            av[u] = fminf(fmaxf(a2, -1.f), 1.f);
        }
        __syncthreads();                       // all XA reads done
        #pragma unroll
        for (int u = 0; u < 4; ++u) {
            XA[(rbase + ii[u]) * 17 + dd[u]] = av[u];
            B1s[(rbase + ii[u]) * 104 + 64 + dd[u]] = f2bf(av[u]);
        }

        // logp (4 threads per particle)
        {
            int i = t >> 2, jj = t & 3;
            float a1 = 0.f, a2s = 0.f;
            #pragma unroll
            for (int u = 0; u < 8; ++u) {
                int j = jj + 4 * u;
                float kk = KMs[i * 33 + j];
                a1  += kk * PPs[i * 33 + j];
                a2s += (2.f * gamma * D2s[i * 33 + j] - 16.f) * kk;
            }
            a1  += __shfl_xor(a1, 1);  a1  += __shfl_xor(a1, 2);
            a2s += __shfl_xor(a2s, 1); a2s += __shfl_xor(a2s, 2);
            if (jj == 0) {
                float tmp1 = -2.f * gamma * a1  * (1.f / 32.f);
                float tmp2 = -2.f * gamma * a2s * (1.f / 32.f);
                LG[rbase + i] -= 0.1f * (tmp1 + tmp2);
            }
        }
        __syncthreads();                       // XA/B1s/LG settled; B0u free
    }

    // ---- final outputs: a (from XA) and logp
    for (int u = tid; u < RB * 16; u += 256) {
        int r = u >> 4, d = u & 15;
        out_a[(size_t)row0 * 16 + u] = XA[r * 17 + d];
    }
    if (tid < RB) out_logp[row0 + tid] = LG[tid];
}

// ---------------------------------------------------------------------------
extern "C" void kernel_launch(void* const* d_in, const int* in_sizes, int n_in,
                              void* d_out, int out_size, void* d_ws, size_t ws_size,
                              hipStream_t stream) {
    const float* obs = (const float*)d_in[0];
    const float* a0  = (const float*)d_in[1];
    const float* w1  = (const float*)d_in[2];
    const float* b1  = (const float*)d_in[3];
    const float* w2  = (const float*)d_in[4];
    const float* b2  = (const float*)d_in[5];
    const float* w3  = (const float*)d_in[6];
    const float* b3  = (const float*)d_in[7];

    float* out_a    = (float*)d_out;                 // [BN,16]
    float* out_logp = out_a + (size_t)BNROWS * 16;   // [BN]
    float* out_q    = out_logp + BNROWS;             // [BN]

    char* p = (char*)d_ws;
    ushort* pB1 = (ushort*)p; p += 24576 * 2;
    ushort* pB2 = (ushort*)p; p += 65536 * 2;
    ushort* pB3 = (ushort*)p; p += 65536 * 2;
    ushort* pB4 = (ushort*)p;

    prep_pack<<<78, 256, 0, stream>>>(w1, w2, pB1, pB2, pB3, pB4);

    fused_kernel<<<BNROWS / RB, 256, 0, stream>>>(
        obs, a0, b1, b2, w3, b3, pB1, pB2, pB3, pB4,
        out_a, out_logp, out_q);
}

// Round 6
// 428.233 us; speedup vs baseline: 2.5085x; 2.5085x over previous
//
#include <hip/hip_runtime.h>
#include <hip/hip_bf16.h>
#include <math.h>

#define BNROWS (4096*32)   // 131072
#define RB     64          // rows per MLP block

typedef __attribute__((ext_vector_type(8))) short bf16x8;
typedef __attribute__((ext_vector_type(4))) float f32x4;

static __device__ __forceinline__ ushort f2bf(float x) {
    union { __hip_bfloat16 h; ushort u; } cv;
    cv.h = __float2bfloat16(x);
    return cv.u;
}

// ---------------------------------------------------------------------------
// obs -> bf16 once per launch (obs is reused by all 3 mlp dispatches).
__global__ void obs_to_bf16(const float* __restrict__ obs,
                            ushort* __restrict__ obs_bf) {
    size_t i = ((size_t)blockIdx.x * 256 + threadIdx.x) * 4;
    float4 v = *(const float4*)&obs[i];
    ushort4 o;
    o.x = f2bf(v.x); o.y = f2bf(v.y); o.z = f2bf(v.z); o.w = f2bf(v.w);
    *(ushort4*)&obs_bf[i] = o;
}

// ---------------------------------------------------------------------------
// Pack weights into MFMA fragment order (lane-contiguous 16B loads).
// Lane (q,m): element j -> W[k = c*32 + q*8 + j][n = tile*16 + m].
// Used as the A-operand (A[m][k] lane map == B[k][n] lane map), giving the
// transposed product so activation C/D fragments are row-contiguous.
__global__ void prep_pack(const float* __restrict__ w1,
                          const float* __restrict__ w2,
                          ushort* __restrict__ pB1, ushort* __restrict__ pB2,
                          ushort* __restrict__ pB3, ushort* __restrict__ pB4) {
    int g = blockIdx.x * 256 + threadIdx.x;   // 19968 total
    ushort out[8];
    ushort* dst;
    if (g < 3072) {
        int lane = g & 63, gc = g >> 6;
        int t = gc / 3, c = gc % 3;
        int m = lane & 15, q = lane >> 4, n = t * 16 + m;
        #pragma unroll
        for (int j = 0; j < 8; ++j) {
            int k = c * 32 + q * 8 + j;
            out[j] = f2bf((k < 80) ? w1[k * 256 + n] : 0.f);
        }
        dst = &pB1[g * 8];
    } else if (g < 11264) {
        int gg = g - 3072;
        int lane = gg & 63, gc = gg >> 6;
        int t = gc >> 3, c = gc & 7;
        int m = lane & 15, q = lane >> 4, n = t * 16 + m;
        #pragma unroll
        for (int j = 0; j < 8; ++j)
            out[j] = f2bf(w2[(c * 32 + q * 8 + j) * 256 + n]);
        dst = &pB2[gg * 8];
    } else if (g < 19456) {
        int gg = g - 11264;
        int lane = gg & 63, gc = gg >> 6;
        int t = gc >> 3, c = gc & 7;
        int m = lane & 15, q = lane >> 4;
        #pragma unroll
        for (int j = 0; j < 8; ++j)
            out[j] = f2bf(w2[(t * 16 + m) * 256 + c * 32 + q * 8 + j]);
        dst = &pB3[gg * 8];
    } else if (g < 19968) {
        int gg = g - 19456;
        int lane = gg & 63, c = gg >> 6;
        int m = lane & 15, q = lane >> 4;
        #pragma unroll
        for (int j = 0; j < 8; ++j)
            out[j] = f2bf(w1[(64 + m) * 256 + c * 32 + q * 8 + j]);
        dst = &pB4[gg * 8];
    } else return;
    *(uint4*)dst = *(uint4*)out;
}

// ---------------------------------------------------------------------------
// Fused critic forward + VJP wrt actions, bf16 MFMA with SWAPPED operands:
//   mfma(W_frag, act_frag, acc) computes the transposed tile, so each lane's
//   C/D fragment = 4 consecutive COLUMNS of one row -> ds_write_b64 epilogues
//   (round-4 row-major layout needed 4x ds_write_b16).
// acc[rt][tc][i] <-> z[row = rt*16 + (lane&15)][col = (w*4+tc)*16 + q*4 + i];
// identical mapping in phases B and D, so the relu mask aligns.
// Plain __launch_bounds__(256): min-wave bounds caused scratch spill
// (round 3: svgd 1 GB; round 4: mlp 150 MB; round 5: fused 2.1 GB).
__global__ __launch_bounds__(256) void mlp_mfma(
    const ushort* __restrict__ obs_bf,  // [BN,64] bf16
    const float* __restrict__ a_in,     // [BN,16]
    const float* __restrict__ b1,       // [256]
    const float* __restrict__ b2,       // [256]
    const float* __restrict__ w3,       // [256]
    const float* __restrict__ b3,       // [1]
    const ushort* __restrict__ pB1, const ushort* __restrict__ pB2,
    const ushort* __restrict__ pB3, const ushort* __restrict__ pB4,
    float* __restrict__ score,          // [BN,16]
    float* __restrict__ qout)           // [BN]
{
    __shared__ __align__(16) ushort B0[RB * 264];   // h1 -> dz2 -> dz1
    __shared__ __align__(16) ushort B1s[RB * 104];  // h0
    __shared__ float qpart[4][RB];
    __shared__ float bias1[256], bias2[256], w3s[256];

    const int tid  = threadIdx.x;
    const int row0 = blockIdx.x * RB;

    // ---- Phase A: stage h0 = [obs_bf16 | a->bf16 | 0pad] at stride 104
    for (int u = tid; u < 512; u += 256) {                 // obs: 64r x 8 chunks
        int r = u >> 3, ch = u & 7;
        *(uint4*)&B1s[r * 104 + ch * 8] =
            *(const uint4*)&obs_bf[(size_t)(row0 + r) * 64 + ch * 8];
    }
    {                                                      // actions + pad
        int r = tid >> 2, d0 = (tid & 3) * 4;
        float4 av = *(const float4*)&a_in[(size_t)(row0 + r) * 16 + d0];
        ushort4 pv;
        pv.x = f2bf(av.x); pv.y = f2bf(av.y); pv.z = f2bf(av.z); pv.w = f2bf(av.w);
        *(ushort4*)&B1s[r * 104 + 64 + d0] = pv;
        ushort4 zv; zv.x = zv.y = zv.z = zv.w = 0;
        *(ushort4*)&B1s[r * 104 + 80 + d0] = zv;
    }
    if (tid < 256) { bias1[tid] = b1[tid]; bias2[tid] = b2[tid]; w3s[tid] = w3[tid]; }
    __syncthreads();                                       // (1)

    const int lane = tid & 63;
    const int w    = tid >> 6;
    const int m    = lane & 15;
    const int q    = lane >> 4;
    const int qk   = q * 8;

    f32x4 acc[4][4];                 // [row-tile][col-tile], transposed product
    unsigned long long relumask = 0ULL;

    // ---- Phase B: z1 = h0 @ w1 (+b1 in epilogue) ; relu -> B0 ; mask -> regs
    #pragma unroll
    for (int tc = 0; tc < 4; ++tc)
        #pragma unroll
        for (int rt = 0; rt < 4; ++rt) acc[rt][tc] = (f32x4){0.f, 0.f, 0.f, 0.f};
    for (int c = 0; c < 3; ++c) {
        bf16x8 af[4];
        #pragma unroll
        for (int rt = 0; rt < 4; ++rt)
            af[rt] = *(const bf16x8*)&B1s[(rt * 16 + m) * 104 + c * 32 + qk];
        #pragma unroll
        for (int tc = 0; tc < 4; ++tc) {
            bf16x8 wfr = *(const bf16x8*)&pB1[(((w * 4 + tc) * 3 + c) * 64 + lane) * 8];
            #pragma unroll
            for (int rt = 0; rt < 4; ++rt)
                acc[rt][tc] = __builtin_amdgcn_mfma_f32_16x16x32_bf16(wfr, af[rt], acc[rt][tc], 0, 0, 0);
        }
    }
    #pragma unroll
    for (int tc = 0; tc < 4; ++tc) {
        const float4 bv = *(const float4*)&bias1[(w * 4 + tc) * 16 + q * 4];
        const float bva[4] = {bv.x, bv.y, bv.z, bv.w};
        #pragma unroll
        for (int rt = 0; rt < 4; ++rt) {
            ushort4 pk;
            float z0 = acc[rt][tc][0] + bva[0];
            float z1 = acc[rt][tc][1] + bva[1];
            float z2 = acc[rt][tc][2] + bva[2];
            float z3 = acc[rt][tc][3] + bva[3];
            if (z0 > 0.f) relumask |= 1ULL << (rt * 16 + tc * 4 + 0);
            if (z1 > 0.f) relumask |= 1ULL << (rt * 16 + tc * 4 + 1);
            if (z2 > 0.f) relumask |= 1ULL << (rt * 16 + tc * 4 + 2);
            if (z3 > 0.f) relumask |= 1ULL << (rt * 16 + tc * 4 + 3);
            pk.x = f2bf(fmaxf(z0, 0.f)); pk.y = f2bf(fmaxf(z1, 0.f));
            pk.z = f2bf(fmaxf(z2, 0.f)); pk.w = f2bf(fmaxf(z3, 0.f));
            *(ushort4*)&B0[(rt * 16 + m) * 264 + (w * 4 + tc) * 16 + q * 4] = pk;
        }
    }
    __syncthreads();                                       // (2)

    // ---- Phase C: z2 = h1 @ w2 (+b2) ; q partials ; dz2 -> B0
    #pragma unroll
    for (int tc = 0; tc < 4; ++tc)
        #pragma unroll
        for (int rt = 0; rt < 4; ++rt) acc[rt][tc] = (f32x4){0.f, 0.f, 0.f, 0.f};
    for (int c = 0; c < 8; ++c) {
        bf16x8 af[4];
        #pragma unroll
        for (int rt = 0; rt < 4; ++rt)
            af[rt] = *(const bf16x8*)&B0[(rt * 16 + m) * 264 + c * 32 + qk];
        #pragma unroll
        for (int tc = 0; tc < 4; ++tc) {
            bf16x8 wfr = *(const bf16x8*)&pB2[(((w * 4 + tc) * 8 + c) * 64 + lane) * 8];
            #pragma unroll
            for (int rt = 0; rt < 4; ++rt)
                acc[rt][tc] = __builtin_amdgcn_mfma_f32_16x16x32_bf16(wfr, af[rt], acc[rt][tc], 0, 0, 0);
        }
    }
    __syncthreads();                                       // (3) h1 reads done
    {
        float qp[4] = {0.f, 0.f, 0.f, 0.f};                // per row-tile
        #pragma unroll
        for (int tc = 0; tc < 4; ++tc) {
            const float4 bv = *(const float4*)&bias2[(w * 4 + tc) * 16 + q * 4];
            const float4 wv = *(const float4*)&w3s[(w * 4 + tc) * 16 + q * 4];
            const float bva[4] = {bv.x, bv.y, bv.z, bv.w};
            const float wva[4] = {wv.x, wv.y, wv.z, wv.w};
            #pragma unroll
            for (int rt = 0; rt < 4; ++rt) {
                ushort4 pk; float dz[4];
                #pragma unroll
                for (int i = 0; i < 4; ++i) {
                    float z = acc[rt][tc][i] + bva[i];
                    if (z > 0.f) { qp[rt] += z * wva[i]; dz[i] = wva[i]; }
                    else         { dz[i] = 0.f; }
                }
                pk.x = f2bf(dz[0]); pk.y = f2bf(dz[1]);
                pk.z = f2bf(dz[2]); pk.w = f2bf(dz[3]);
                *(ushort4*)&B0[(rt * 16 + m) * 264 + (w * 4 + tc) * 16 + q * 4] = pk;
            }
        }
        #pragma unroll
        for (int rt = 0; rt < 4; ++rt) {
            float v = qp[rt];
            v += __shfl_xor(v, 16); v += __shfl_xor(v, 32);   // sum 4 q-lanes
            if (q == 0) qpart[w][rt * 16 + m] = v;
        }
    }
    __syncthreads();                                       // (4) dz2 visible

    if (tid < RB)
        qout[row0 + tid] = qpart[0][tid] + qpart[1][tid] + qpart[2][tid] +
                           qpart[3][tid] + b3[0];

    // ---- Phase D: dh1 = dz2 @ w2^T ; dz1 = dh1 * mask -> B0
    #pragma unroll
    for (int tc = 0; tc < 4; ++tc)
        #pragma unroll
        for (int rt = 0; rt < 4; ++rt) acc[rt][tc] = (f32x4){0.f, 0.f, 0.f, 0.f};
    for (int c = 0; c < 8; ++c) {
        bf16x8 af[4];
        #pragma unroll
        for (int rt = 0; rt < 4; ++rt)
            af[rt] = *(const bf16x8*)&B0[(rt * 16 + m) * 264 + c * 32 + qk];
        #pragma unroll
        for (int tc = 0; tc < 4; ++tc) {
            bf16x8 wfr = *(const bf16x8*)&pB3[(((w * 4 + tc) * 8 + c) * 64 + lane) * 8];
            #pragma unroll
            for (int rt = 0; rt < 4; ++rt)
                acc[rt][tc] = __builtin_amdgcn_mfma_f32_16x16x32_bf16(wfr, af[rt], acc[rt][tc], 0, 0, 0);
        }
    }
    __syncthreads();                                       // (5) dz2 reads done
    #pragma unroll
    for (int rt = 0; rt < 4; ++rt)
        #pragma unroll
        for (int tc = 0; tc < 4; ++tc) {
            ushort4 pk;
            pk.x = f2bf((relumask >> (rt * 16 + tc * 4 + 0)) & 1ULL ? acc[rt][tc][0] : 0.f);
            pk.y = f2bf((relumask >> (rt * 16 + tc * 4 + 1)) & 1ULL ? acc[rt][tc][1] : 0.f);
            pk.z = f2bf((relumask >> (rt * 16 + tc * 4 + 2)) & 1ULL ? acc[rt][tc][2] : 0.f);
            pk.w = f2bf((relumask >> (rt * 16 + tc * 4 + 3)) & 1ULL ? acc[rt][tc][3] : 0.f);
            *(ushort4*)&B0[(rt * 16 + m) * 264 + (w * 4 + tc) * 16 + q * 4] = pk;
        }
    __syncthreads();                                       // (6)

    // ---- Phase E: score = dz1 @ w1[64:80]^T  (wave w -> row-tile w)
    {
        f32x4 acc2 = (f32x4){0.f, 0.f, 0.f, 0.f};
        for (int c = 0; c < 8; ++c) {
            bf16x8 af = *(const bf16x8*)&B0[(w * 16 + m) * 264 + c * 32 + qk];
            bf16x8 wfr = *(const bf16x8*)&pB4[(c * 64 + lane) * 8];
            acc2 = __builtin_amdgcn_mfma_f32_16x16x32_bf16(wfr, af, acc2, 0, 0, 0);
        }
        float4 o; o.x = acc2[0]; o.y = acc2[1]; o.z = acc2[2]; o.w = acc2[3];
        *(float4*)&score[(size_t)(row0 + w * 16 + m) * 16 + q * 4] = o;
    }
}

// ---------------------------------------------------------------------------
// SVGD update: one block per state. Median via 4-pass radix select on float
// bits (nonneg floats order as u32) -> bit-exact jnp.median. Conflict-free
// LDS strides (17 for [32x16], 33 for [32x32]).
// launch_bounds(256,4): 128-VGPR budget. (256,8) forced 32 VGPRs -> scratch
// spills -> 1 GB/dispatch HBM traffic (round-3 post-mortem). Do not re-tighten.
__global__ __launch_bounds__(256, 4) void svgd_kernel(
    const float* __restrict__ a_in,    // [BN,16]
    const float* __restrict__ score,   // [BN,16]
    const float* __restrict__ logp_in, // [BN] (ignored if first)
    float* __restrict__ logp_out,      // [BN]
    float* __restrict__ a_out,         // [BN,16]
    int first)
{
    __shared__ float X[32 * 17], S[32 * 17];
    __shared__ float D2[32 * 33], KM[32 * 33], P[32 * 33];
    __shared__ int hist[256];
    __shared__ int wsum[4];
    __shared__ int bbin, bexcl;
    __shared__ float medsh;
    __shared__ int redc[4];
    __shared__ unsigned redm[4];

    const int b = blockIdx.x, tid = threadIdx.x;
    const int lane = tid & 63, wv = tid >> 6;
    const size_t base = (size_t)b * 512;

    for (int idx = tid; idx < 512; idx += 256) {
        int r = idx >> 4, d = idx & 15;
        X[r * 17 + d] = a_in[base + idx];
        S[r * 17 + d] = score[base + idx];
    }
    __syncthreads();

    unsigned v[4];                       // this thread's 4 dist^2 values (bits)
    #pragma unroll
    for (int t = 0; t < 4; ++t) {
        int idx = tid + 256 * t, i = idx >> 5, j = idx & 31;
        float s = 0.f;
        #pragma unroll
        for (int d = 0; d < 16; ++d) {
            float df = X[i * 17 + d] - X[j * 17 + d];
            s += df * df;
        }
        D2[i * 33 + j] = s;
        v[t] = __float_as_uint(s);
    }

    // radix select: find rank-511 (0-indexed) value
    unsigned prefix = 0;
    int rank = 511;
    for (int shift = 24; shift >= 0; shift -= 8) {
        hist[tid] = 0;
        __syncthreads();
        unsigned him = (shift == 24) ? 0u : (0xFFFFFFFFu << (shift + 8));
        #pragma unroll
        for (int t = 0; t < 4; ++t)
            if ((v[t] & him) == prefix)
                atomicAdd(&hist[(v[t] >> shift) & 255], 1);
        __syncthreads();
        int c = hist[tid], inc = c;
        #pragma unroll
        for (int off = 1; off < 64; off <<= 1) {
            int tt = __shfl_up(inc, off, 64);
            if (lane >= off) inc += tt;
        }
        if (lane == 63) wsum[wv] = inc;
        __syncthreads();
        int basec = 0;
        for (int ww = 0; ww < wv; ++ww) basec += wsum[ww];
        int excl = basec + inc - c;
        if (c > 0 && rank >= excl && rank < excl + c) { bbin = tid; bexcl = excl; }
        __syncthreads();
        prefix |= ((unsigned)bbin << shift);
        rank -= bexcl;
    }
    const float v1 = __uint_as_float(prefix);

    // rank-512 value: v1 again if count(x<=v1)>=513 else min of x>v1
    {
        int cle = 0;
        unsigned mgt = 0xFFFFFFFFu;
        #pragma unroll
        for (int t = 0; t < 4; ++t) {
            if (v[t] <= prefix) cle++;
            else mgt = min(mgt, v[t]);
        }
        #pragma unroll
        for (int off = 1; off < 64; off <<= 1) {
            cle += __shfl_xor(cle, off);
            mgt = min(mgt, (unsigned)__shfl_xor((int)mgt, off));
        }
        if (lane == 0) { redc[wv] = cle; redm[wv] = mgt; }
        __syncthreads();
        if (tid == 0) {
            int C = redc[0] + redc[1] + redc[2] + redc[3];
            unsigned M = min(min(redm[0], redm[1]), min(redm[2], redm[3]));
            float v2 = (C >= 513) ? v1 : __uint_as_float(M);
            medsh = 0.5f * (v1 + v2);
        }
        __syncthreads();
    }
    const float med   = medsh;
    const float gamma = 1.0f / (2.0f * (med / 3.4657359027997265f + 1e-8f));

    // K and P[i][j] = sum_d diff[i,j,d] * S[j,d]
    #pragma unroll
    for (int t = 0; t < 4; ++t) {
        int idx = tid + 256 * t, i = idx >> 5, j = idx & 31;
        KM[i * 33 + j] = __expf(-gamma * __uint_as_float(v[t]));
        float p = 0.f;
        #pragma unroll
        for (int d = 0; d < 16; ++d)
            p += (X[i * 17 + d] - X[j * 17 + d]) * S[j * 17 + d];
        P[i * 33 + j] = p;
    }
    __syncthreads();

    // phi + particle update
    for (int idx = tid; idx < 512; idx += 256) {
        int i = idx >> 4, d = idx & 15;
        float s1 = 0.f, s2 = 0.f;
        float xi = X[i * 17 + d];
        #pragma unroll
        for (int j = 0; j < 32; ++j) {
            float kk = KM[i * 33 + j];
            s1 += kk * S[j * 17 + d];
            s2 += (xi - X[j * 17 + d]) * kk;
        }
        float phi = (s1 + 2.f * gamma * s2) * (1.f / 32.f);
        float av = xi + 0.1f * phi;
        av = fminf(fmaxf(av, -1.f), 1.f);
        a_out[base + idx] = av;
    }

    // logp correction (256 threads: i = tid>>3, 8 lanes reduce over j)
    {
        int i = tid >> 3, jj = tid & 7;
        float acc1 = 0.f, acc2 = 0.f;
        #pragma unroll
        for (int t = 0; t < 4; ++t) {
            int j = jj + 8 * t;
            float kk = KM[i * 33 + j];
            acc1 += kk * P[i * 33 + j];
            acc2 += (2.f * gamma * D2[i * 33 + j] - 16.f) * kk;
        }
        acc1 += __shfl_xor(acc1, 1); acc1 += __shfl_xor(acc1, 2); acc1 += __shfl_xor(acc1, 4);
        acc2 += __shfl_xor(acc2, 1); acc2 += __shfl_xor(acc2, 2); acc2 += __shfl_xor(acc2, 4);
        if (jj == 0) {
            float tmp1 = -2.f * gamma * acc1 * (1.f / 32.f);
            float tmp2 = -2.f * gamma * acc2 * (1.f / 32.f);
            float prev = first ? 0.f : logp_in[b * 32 + i];
            logp_out[b * 32 + i] = prev - 0.1f * (tmp1 + tmp2);
        }
    }
}

// ---------------------------------------------------------------------------
extern "C" void kernel_launch(void* const* d_in, const int* in_sizes, int n_in,
                              void* d_out, int out_size, void* d_ws, size_t ws_size,
                              hipStream_t stream) {
    const float* obs = (const float*)d_in[0];
    const float* a0  = (const float*)d_in[1];
    const float* w1  = (const float*)d_in[2];
    const float* b1  = (const float*)d_in[3];
    const float* w2  = (const float*)d_in[4];
    const float* b2  = (const float*)d_in[5];
    const float* w3  = (const float*)d_in[6];
    const float* b3  = (const float*)d_in[7];

    float* out_a    = (float*)d_out;                 // [BN,16]
    float* out_logp = out_a + (size_t)BNROWS * 16;   // [BN]
    float* out_q    = out_logp + BNROWS;             // [BN]

    char* p = (char*)d_ws;
    ushort* pB1 = (ushort*)p; p += 24576 * 2;
    ushort* pB2 = (ushort*)p; p += 65536 * 2;
    ushort* pB3 = (ushort*)p; p += 65536 * 2;
    ushort* pB4 = (ushort*)p; p += 4096 * 2;
    ushort* obs_bf = (ushort*)p; p += (size_t)BNROWS * 64 * 2;
    float* abuf0 = (float*)p; p += (size_t)BNROWS * 16 * 4;
    float* abuf1 = (float*)p; p += (size_t)BNROWS * 16 * 4;
    float* scr   = (float*)p; p += (size_t)BNROWS * 16 * 4;
    float* logp  = (float*)p; p += (size_t)BNROWS * 4;
    float* qtmp  = (float*)p;

    prep_pack<<<78, 256, 0, stream>>>(w1, w2, pB1, pB2, pB3, pB4);
    obs_to_bf16<<<8192, 256, 0, stream>>>(obs, obs_bf);

    const int MB = BNROWS / RB;   // 2048 blocks

    // step 1
    mlp_mfma<<<MB, 256, 0, stream>>>(obs_bf, a0, b1, b2, w3, b3,
                                     pB1, pB2, pB3, pB4, scr, qtmp);
    svgd_kernel<<<4096, 256, 0, stream>>>(a0, scr, nullptr, logp, abuf0, 1);
    // step 2
    mlp_mfma<<<MB, 256, 0, stream>>>(obs_bf, abuf0, b1, b2, w3, b3,
                                     pB1, pB2, pB3, pB4, scr, qtmp);
    svgd_kernel<<<4096, 256, 0, stream>>>(abuf0, scr, logp, logp, abuf1, 0);
    // step 3 (q of this step is the q_vals output)
    mlp_mfma<<<MB, 256, 0, stream>>>(obs_bf, abuf1, b1, b2, w3, b3,
                                     pB1, pB2, pB3, pB4, scr, out_q);
    svgd_kernel<<<4096, 256, 0, stream>>>(abuf1, scr, logp, out_logp, out_a, 0);
}